// Round 8
// baseline (359.366 us; speedup 1.0000x reference)
//
#include <hip/hip_runtime.h>
#include <hip/hip_bf16.h>
#include <math.h>

#define BB 64
#define OO 32
#define II 2048
#define DD 16
#define CAPS_EPS 1e-12f
#define T_CONST 5.6312118f   // ln(0.9*31) - ln(0.1)

#define GX 256               // i-chunks for s/d passes (8 blocks/CU)
#define TI 8                 // II/GX

// workspace float offsets
#define OFF_DSUM 0ULL
#define OFF_V     16ULL                        // 32768: v [B][O][D]
#define OFF_UNORM 32784ULL                     // 131072: unorm [I][B]
#define OFF_UBF   163856ULL                    // 1048576 slots: u bf16 [I][B][16k]
#define OFF_WB    1212432ULL                   // 8388608 slots: W bf16 A-frag
#define OFF_DD    9601040ULL                   // 4194304: d [I][O][B]
#define OFF_CB    13795344ULL                  // 4194304: c [I][O][B]
#define OFF_PART  17989648ULL                  // GX*32768 = 8388608: part [GX][O][B][D]

typedef __attribute__((ext_vector_type(8))) short bf16x8;
typedef __attribute__((ext_vector_type(4))) float f32x4;

union AU { bf16x8 v; unsigned short h[8]; uint4 u4; };

__device__ __forceinline__ unsigned short f2bf(float x) {
    __hip_bfloat16 h = __float2bfloat16(x);
    unsigned short s; __builtin_memcpy(&s, &h, 2); return s;
}

// -------- uprep: u -> bf16 [i][b][16], unorm[i][b], zero dsums --------
__global__ __launch_bounds__(256) void uprep_kernel(
    const float* __restrict__ u, float* __restrict__ ws)
{
    const int gid = blockIdx.x * 256 + threadIdx.x;   // 131072
    if (gid < 2) ws[OFF_DSUM + gid] = 0.f;
    const int i = gid >> 6, b = gid & 63;

    const float4* up = reinterpret_cast<const float4*>(u + ((size_t)b * II + i) * DD);
    float4 t0 = up[0], t1 = up[1], t2 = up[2], t3 = up[3];
    float un2 = t0.x*t0.x + t0.y*t0.y + t0.z*t0.z + t0.w*t0.w
              + t1.x*t1.x + t1.y*t1.y + t1.z*t1.z + t1.w*t1.w
              + t2.x*t2.x + t2.y*t2.y + t2.z*t2.z + t2.w*t2.w
              + t3.x*t3.x + t3.y*t3.y + t3.z*t3.z + t3.w*t3.w;
    ws[OFF_UNORM + (size_t)i * 64 + b] = sqrtf(un2);

    AU a0, a1;
    a0.h[0]=f2bf(t0.x); a0.h[1]=f2bf(t0.y); a0.h[2]=f2bf(t0.z); a0.h[3]=f2bf(t0.w);
    a0.h[4]=f2bf(t1.x); a0.h[5]=f2bf(t1.y); a0.h[6]=f2bf(t1.z); a0.h[7]=f2bf(t1.w);
    a1.h[0]=f2bf(t2.x); a1.h[1]=f2bf(t2.y); a1.h[2]=f2bf(t2.z); a1.h[3]=f2bf(t2.w);
    a1.h[4]=f2bf(t3.x); a1.h[5]=f2bf(t3.y); a1.h[6]=f2bf(t3.z); a1.h[7]=f2bf(t3.w);
    unsigned short* ubf = (unsigned short*)(ws + OFF_UBF);
    uint4* dst = reinterpret_cast<uint4*>(ubf + ((size_t)i * 64 + b) * 16);
    dst[0] = a0.u4; dst[1] = a1.u4;
}

// -------- s0w: W fp32 -> Wb bf16 (A-layout) + MFMA uhat + s0 partials --------
__global__ __launch_bounds__(256) void s0w_kernel(
    const float* __restrict__ W, float* __restrict__ ws)
{
    const int og   = blockIdx.y;
    const int wave = threadIdx.x >> 6;
    const int lane = threadIdx.x & 63;
    const int o    = og * 4 + wave;
    const int q    = lane >> 4;
    const int n    = lane & 15;

    unsigned short* Wb = (unsigned short*)(ws + OFF_WB);
    const unsigned short* ubf = (const unsigned short*)(ws + OFF_UBF);
    const float* unorm = ws + OFF_UNORM;
    float* part = ws + OFF_PART;

    f32x4 s_acc[4];
    #pragma unroll
    for (int g = 0; g < 4; ++g) s_acc[g] = (f32x4){0.f, 0.f, 0.f, 0.f};

    for (int ii = 0; ii < TI; ++ii) {
        const int i = blockIdx.x * TI + ii;

        AU au; au.u4 = make_uint4(0, 0, 0, 0);
        if (q < 2) {
            const float* wp = W + (((size_t)o * II + i) * 16 + n) * 16 + q * 8;
            float4 w0 = *(const float4*)(wp);
            float4 w1 = *(const float4*)(wp + 4);
            au.h[0]=f2bf(w0.x); au.h[1]=f2bf(w0.y); au.h[2]=f2bf(w0.z); au.h[3]=f2bf(w0.w);
            au.h[4]=f2bf(w1.x); au.h[5]=f2bf(w1.y); au.h[6]=f2bf(w1.z); au.h[7]=f2bf(w1.w);
            *reinterpret_cast<uint4*>(Wb + (((size_t)o * II + i) * 2 + q) * 128 + n * 8) = au.u4;
        }

        f32x4 d4[4];
        #pragma unroll
        for (int g = 0; g < 4; ++g) {
            AU bu;
            bu.u4 = *reinterpret_cast<const uint4*>(
                ubf + ((size_t)i * 64 + g * 16 + n) * 16 + (q & 1) * 8);
            d4[g] = __builtin_amdgcn_mfma_f32_16x16x32_bf16(
                au.v, bu.v, (f32x4){0.f, 0.f, 0.f, 0.f}, 0, 0, 0);
        }

        #pragma unroll
        for (int g = 0; g < 4; ++g) {
            float n2 = d4[g][0]*d4[g][0] + d4[g][1]*d4[g][1]
                     + d4[g][2]*d4[g][2] + d4[g][3]*d4[g][3];
            n2 += __shfl_xor(n2, 16);
            n2 += __shfl_xor(n2, 32);
            const float rawn = sqrtf(n2);
            const float un = unorm[(size_t)i * 64 + g * 16 + n];
            const float cs = (1.0f / 32.0f) * fminf(rawn, un) / (rawn + CAPS_EPS);
            s_acc[g][0] += cs * d4[g][0];
            s_acc[g][1] += cs * d4[g][1];
            s_acc[g][2] += cs * d4[g][2];
            s_acc[g][3] += cs * d4[g][3];
        }
    }

    #pragma unroll
    for (int g = 0; g < 4; ++g) {
        float4 v = make_float4(s_acc[g][0], s_acc[g][1], s_acc[g][2], s_acc[g][3]);
        *reinterpret_cast<float4*>(
            part + (((size_t)blockIdx.x * OO + o) * 64 + g * 16 + n) * 16 + q * 4) = v;
    }
}

// -------- dpass: dist[i][o][b] = ||v - scale*uhat||, atomic dsum --------
template<int SLOT>
__global__ __launch_bounds__(256) void dpass_kernel(float* __restrict__ ws)
{
    const int og   = blockIdx.y;
    const int wave = threadIdx.x >> 6;
    const int lane = threadIdx.x & 63;
    const int o    = og * 4 + wave;
    const int q    = lane >> 4;
    const int n    = lane & 15;

    const unsigned short* Wb  = (const unsigned short*)(ws + OFF_WB);
    const unsigned short* ubf = (const unsigned short*)(ws + OFF_UBF);
    const float* unorm = ws + OFF_UNORM;
    const float* v_ws  = ws + OFF_V;
    float* dws = ws + OFF_DD;

    f32x4 vreg[4];
    #pragma unroll
    for (int g = 0; g < 4; ++g)
        vreg[g] = *reinterpret_cast<const f32x4*>(
            v_ws + ((size_t)(g * 16 + n) * OO + o) * 16 + q * 4);

    float dsum_local = 0.f;

    for (int ii = 0; ii < TI; ++ii) {
        const int i = blockIdx.x * TI + ii;

        AU au; au.u4 = make_uint4(0, 0, 0, 0);
        if (q < 2)
            au.u4 = *reinterpret_cast<const uint4*>(
                Wb + (((size_t)o * II + i) * 2 + q) * 128 + n * 8);

        f32x4 d4[4];
        #pragma unroll
        for (int g = 0; g < 4; ++g) {
            AU bu;
            bu.u4 = *reinterpret_cast<const uint4*>(
                ubf + ((size_t)i * 64 + g * 16 + n) * 16 + (q & 1) * 8);
            d4[g] = __builtin_amdgcn_mfma_f32_16x16x32_bf16(
                au.v, bu.v, (f32x4){0.f, 0.f, 0.f, 0.f}, 0, 0, 0);
        }

        #pragma unroll
        for (int g = 0; g < 4; ++g) {
            float n2 = d4[g][0]*d4[g][0] + d4[g][1]*d4[g][1]
                     + d4[g][2]*d4[g][2] + d4[g][3]*d4[g][3];
            n2 += __shfl_xor(n2, 16);
            n2 += __shfl_xor(n2, 32);
            const float rawn = sqrtf(n2);
            const float un = unorm[(size_t)i * 64 + g * 16 + n];
            const float scale = fminf(rawn, un) / (rawn + CAPS_EPS);
            float dd2 = 0.f;
            #pragma unroll
            for (int r = 0; r < 4; ++r) {
                float df = vreg[g][r] - scale * d4[g][r];
                dd2 += df * df;
            }
            dd2 += __shfl_xor(dd2, 16);
            dd2 += __shfl_xor(dd2, 32);
            const float dist = sqrtf(dd2);
            if (q == 0) {
                dws[((size_t)i * OO + o) * 64 + g * 16 + n] = dist;
                dsum_local += dist;
            }
        }
    }

    #pragma unroll
    for (int off = 32; off > 0; off >>= 1)
        dsum_local += __shfl_down(dsum_local, off);
    __shared__ float red[4];
    if (lane == 0) red[wave] = dsum_local;
    __syncthreads();
    if (threadIdx.x == 0)
        atomicAdd(&ws[OFF_DSUM + SLOT], red[0] + red[1] + red[2] + red[3]);
}

// -------- csoft: c[i][o][b] = softmax_o(t * d), t from global dsum --------
template<int SLOT>
__global__ __launch_bounds__(256) void csoft_kernel(float* __restrict__ ws)
{
    const int wave = threadIdx.x >> 6;
    const int b    = threadIdx.x & 63;
    const int i    = blockIdx.x * 4 + wave;

    const float* dws = ws + OFF_DD;
    float* cb = ws + OFF_CB;
    const float dsum = ws[OFF_DSUM + SLOT];
    const float tval = T_CONST / (-0.5f * dsum * (1.0f / 4194304.0f) + 1e-12f);

    float dv[OO];
    #pragma unroll
    for (int o = 0; o < OO; ++o)
        dv[o] = tval * dws[((size_t)i * OO + o) * 64 + b];
    float m = -1e30f;
    #pragma unroll
    for (int o = 0; o < OO; ++o) m = fmaxf(m, dv[o]);
    float ssum = 0.f;
    #pragma unroll
    for (int o = 0; o < OO; ++o) { dv[o] = __expf(dv[o] - m); ssum += dv[o]; }
    const float inv = 1.f / ssum;
    #pragma unroll
    for (int o = 0; o < OO; ++o)
        cb[((size_t)i * OO + o) * 64 + b] = dv[o] * inv;
}

// -------- spass: s partials = sum_i c * scale * uhat (MFMA recompute) --------
__global__ __launch_bounds__(256) void spass_kernel(float* __restrict__ ws)
{
    const int og   = blockIdx.y;
    const int wave = threadIdx.x >> 6;
    const int lane = threadIdx.x & 63;
    const int o    = og * 4 + wave;
    const int q    = lane >> 4;
    const int n    = lane & 15;

    const unsigned short* Wb  = (const unsigned short*)(ws + OFF_WB);
    const unsigned short* ubf = (const unsigned short*)(ws + OFF_UBF);
    const float* unorm = ws + OFF_UNORM;
    const float* cb = ws + OFF_CB;
    float* part = ws + OFF_PART;

    f32x4 s_acc[4];
    #pragma unroll
    for (int g = 0; g < 4; ++g) s_acc[g] = (f32x4){0.f, 0.f, 0.f, 0.f};

    for (int ii = 0; ii < TI; ++ii) {
        const int i = blockIdx.x * TI + ii;

        AU au; au.u4 = make_uint4(0, 0, 0, 0);
        if (q < 2)
            au.u4 = *reinterpret_cast<const uint4*>(
                Wb + (((size_t)o * II + i) * 2 + q) * 128 + n * 8);

        f32x4 d4[4];
        #pragma unroll
        for (int g = 0; g < 4; ++g) {
            AU bu;
            bu.u4 = *reinterpret_cast<const uint4*>(
                ubf + ((size_t)i * 64 + g * 16 + n) * 16 + (q & 1) * 8);
            d4[g] = __builtin_amdgcn_mfma_f32_16x16x32_bf16(
                au.v, bu.v, (f32x4){0.f, 0.f, 0.f, 0.f}, 0, 0, 0);
        }

        #pragma unroll
        for (int g = 0; g < 4; ++g) {
            float n2 = d4[g][0]*d4[g][0] + d4[g][1]*d4[g][1]
                     + d4[g][2]*d4[g][2] + d4[g][3]*d4[g][3];
            n2 += __shfl_xor(n2, 16);
            n2 += __shfl_xor(n2, 32);
            const float rawn = sqrtf(n2);
            const float un = unorm[(size_t)i * 64 + g * 16 + n];
            const float cc = cb[((size_t)i * OO + o) * 64 + g * 16 + n];
            const float cs = cc * fminf(rawn, un) / (rawn + CAPS_EPS);
            s_acc[g][0] += cs * d4[g][0];
            s_acc[g][1] += cs * d4[g][1];
            s_acc[g][2] += cs * d4[g][2];
            s_acc[g][3] += cs * d4[g][3];
        }
    }

    #pragma unroll
    for (int g = 0; g < 4; ++g) {
        float4 v = make_float4(s_acc[g][0], s_acc[g][1], s_acc[g][2], s_acc[g][3]);
        *reinterpret_cast<float4*>(
            part + (((size_t)blockIdx.x * OO + o) * 64 + g * 16 + n) * 16 + q * 4) = v;
    }
}

// -------- finv: reduce part (+bias) -> squash -> vout --------
__global__ __launch_bounds__(256) void finv_kernel(
    const float* __restrict__ part, const float* __restrict__ bias,
    float* __restrict__ vout)
{
    const int tid = blockIdx.x * 256 + threadIdx.x;  // b*512 + o*16 + d
    const int b = tid >> 9, o = (tid >> 4) & 31, d = tid & 15;
    float s = 0.f;
    for (int ic = 0; ic < GX; ++ic)
        s += part[(((size_t)ic * OO + o) * 64 + b) * 16 + d];
    s += bias[tid & 511];
    float n2 = s * s;
    #pragma unroll
    for (int off = 1; off < 16; off <<= 1) n2 += __shfl_xor(n2, off);
    vout[tid] = s * (n2 / (1.f + n2)) * rsqrtf(n2 + CAPS_EPS);
}

// -------- transpose: c [I][O][B] -> out [B][O][I] --------
__global__ __launch_bounds__(256) void transpose_kernel(
    const float* __restrict__ cb, float* __restrict__ dst)
{
    __shared__ float tile[32][65];
    const int o  = blockIdx.y;
    const int i0 = blockIdx.x * 32;
    #pragma unroll
    for (int k = 0; k < 8; ++k) {
        const int lin = k * 256 + threadIdx.x;
        const int r = lin >> 6, b = lin & 63;
        tile[r][b] = cb[((size_t)(i0 + r) * OO + o) * 64 + b];
    }
    __syncthreads();
    #pragma unroll
    for (int k = 0; k < 8; ++k) {
        const int lin = k * 256 + threadIdx.x;
        const int b = lin >> 5, r = lin & 31;
        dst[((size_t)b * OO + o) * II + i0 + r] = tile[r][b];
    }
}

extern "C" void kernel_launch(void* const* d_in, const int* in_sizes, int n_in,
                              void* d_out, int out_size, void* d_ws, size_t ws_size,
                              hipStream_t stream) {
    const float* u    = (const float*)d_in[0];
    const float* W    = (const float*)d_in[1];
    const float* bias = (const float*)d_in[2];
    float* out = (float*)d_out;
    float* ws  = (float*)d_ws;

    float* part = ws + OFF_PART;
    float* v_ws = ws + OFF_V;
    float* cb   = ws + OFF_CB;
    float* cout = out + (size_t)BB * OO * DD;

    dim3 blk(256);
    dim3 grid_m(GX, 8);

    uprep_kernel<<<512, blk, 0, stream>>>(u, ws);
    s0w_kernel<<<grid_m, blk, 0, stream>>>(W, ws);
    finv_kernel<<<128, blk, 0, stream>>>(part, bias, v_ws);
    dpass_kernel<0><<<grid_m, blk, 0, stream>>>(ws);
    csoft_kernel<0><<<512, blk, 0, stream>>>(ws);
    spass_kernel<<<grid_m, blk, 0, stream>>>(ws);
    finv_kernel<<<128, blk, 0, stream>>>(part, bias, v_ws);
    dpass_kernel<1><<<grid_m, blk, 0, stream>>>(ws);
    csoft_kernel<1><<<512, blk, 0, stream>>>(ws);
    spass_kernel<<<grid_m, blk, 0, stream>>>(ws);
    finv_kernel<<<128, blk, 0, stream>>>(part, bias, out);
    transpose_kernel<<<dim3(64, 32), blk, 0, stream>>>(cb, cout);
}